// Round 13
// baseline (40.431 us; speedup 1.0000x reference)
//
#include <hip/hip_runtime.h>
#include <hip/hip_bf16.h>

#define B_ 8
#define T_ 2048
#define V_ 256
#define D_ 512
#define LEFT_ 16
#define C_LDW 520                    // padded bf16 row width for staged C

typedef float f32x4 __attribute__((ext_vector_type(4)));
typedef short bf16x8 __attribute__((ext_vector_type(8)));
typedef unsigned long long u64;
union FragU { unsigned u[4]; u64 ull[2]; bf16x8 v; };

__device__ __forceinline__ unsigned pack_bf2(float a, float b) {
    __hip_bfloat162 h = __float22bfloat162_rn(make_float2(a, b));
    union { __hip_bfloat162 h; unsigned u; } c; c.h = h; return c.u;
}

// Block = 16 tokens, 8 waves. LDS = 33280 (C) + 2304 (S accum) = 35584 B
// -> 4 blocks/CU x 512 thr = 2048 = full thread cap; 1024-block grid fully resident.
// Phase A K-slice partials are combined via LDS atomicAdd (ds_add_f32) instead of
// an 18 KB per-wave spart buffer (this is what unlocks 4 blocks/CU).
__global__ __launch_bounds__(512)
void attn_cell_kernel(const int* __restrict__ symbols,
                      const float* __restrict__ encodings,
                      const float* __restrict__ M,
                      const float* __restrict__ C,
                      float* __restrict__ out,      // (B,T,1024)
                      float* __restrict__ p_out) {  // (B,T,16)
    __shared__ __align__(16) unsigned short cbuf[32 * C_LDW];  // 33280 B
    __shared__ __align__(16) float spf[16 * 36];               // 2304 B

    const int tid  = threadIdx.x;
    const int lane = tid & 63;
    const int w    = tid >> 6;      // 0..7
    const int q    = lane >> 4;     // 0..3
    const int t    = lane & 15;

    const int blk = blockIdx.x;
    const int b   = blk >> 7;
    const int t0  = (blk & 127) * 16;
    const int* symrow = symbols + b * T_;
    const size_t rowbase = (size_t)b * T_ + t0;

    // ---- zero the score accumulator, then one cheap barrier ----
    for (int i = tid; i < 16 * 36; i += 512) spf[i] = 0.f;
    __syncthreads();

    // per-lane phase-A symbols: rows j = t and t+16
    int sa[2];
    #pragma unroll
    for (int g = 0; g < 2; ++g) {
        int pos = t0 + t + 16 * g - (LEFT_ - 1);
        pos = max(pos, 0); pos = min(pos, T_ - 1);
        sa[g] = symrow[pos];
    }

    // ---- enc load, fused exact-f32 passthrough, pack B-fragments ----
    FragU bf[2];
    {
        const float* ebase = encodings + (rowbase + t) * D_;
        float* obase = out + (rowbase + t) * 1024 + D_;
        #pragma unroll
        for (int kc = 0; kc < 2; ++kc) {
            const int d0 = 64 * w + 32 * kc + 4 * q;
            const float4 e0 = *(const float4*)(ebase + d0);
            const float4 e1 = *(const float4*)(ebase + d0 + 16);
            *(float4*)(obase + d0)      = e0;
            *(float4*)(obase + d0 + 16) = e1;
            bf[kc].u[0] = pack_bf2(e0.x, e0.y); bf[kc].u[1] = pack_bf2(e0.z, e0.w);
            bf[kc].u[2] = pack_bf2(e1.x, e1.y); bf[kc].u[3] = pack_bf2(e1.z, e1.w);
        }
    }

    // ---- stage C rows to LDS (independent of p; overlaps phase A) ----
    #pragma unroll
    for (int i = tid; i < 2048; i += 512) {
        const int j = i >> 6;
        const int g = i & 63;          // 16B source granule (8 f32)
        int pos = t0 - (LEFT_ - 1) + j;
        pos = max(pos, 0); pos = min(pos, T_ - 1);
        const float* src = C + (size_t)symrow[pos] * D_ + g * 8;
        const float4 v0 = ((const float4*)src)[0];
        const float4 v1 = ((const float4*)src)[1];
        u64* dst = (u64*)&cbuf[j * C_LDW + g * 8];
        dst[0] = (u64)pack_bf2(v0.x, v0.y) | ((u64)pack_bf2(v0.z, v0.w) << 32);
        dst[1] = (u64)pack_bf2(v1.x, v1.y) | ((u64)pack_bf2(v1.z, v1.w) << 32);
    }

    // ---- phase A: MFMA partials, M fragments straight from L2 (R10-verified) ----
    f32x4 acc0 = {0.f, 0.f, 0.f, 0.f}, acc1 = {0.f, 0.f, 0.f, 0.f};
    #pragma unroll
    for (int kc = 0; kc < 2; ++kc) {
        const int k0 = 64 * w + 32 * kc + 4 * q;
        {
            const float* ma = M + (size_t)sa[0] * D_ + k0;
            const float4 x0 = *(const float4*)ma;
            const float4 x1 = *(const float4*)(ma + 16);
            FragU af;
            af.u[0] = pack_bf2(x0.x, x0.y); af.u[1] = pack_bf2(x0.z, x0.w);
            af.u[2] = pack_bf2(x1.x, x1.y); af.u[3] = pack_bf2(x1.z, x1.w);
            acc0 = __builtin_amdgcn_mfma_f32_16x16x32_bf16(af.v, bf[kc].v, acc0, 0, 0, 0);
        }
        {
            const float* ma = M + (size_t)sa[1] * D_ + k0;
            const float4 x0 = *(const float4*)ma;
            const float4 x1 = *(const float4*)(ma + 16);
            FragU af;
            af.u[0] = pack_bf2(x0.x, x0.y); af.u[1] = pack_bf2(x0.z, x0.w);
            af.u[2] = pack_bf2(x1.x, x1.y); af.u[3] = pack_bf2(x1.z, x1.w);
            acc1 = __builtin_amdgcn_mfma_f32_16x16x32_bf16(af.v, bf[kc].v, acc1, 0, 0, 0);
        }
    }
    // combine K-slices across waves via LDS float atomics (order-noise << threshold)
    #pragma unroll
    for (int r = 0; r < 4; ++r) {
        atomicAdd(&spf[t * 36 + 4 * q + r],      acc0[r]);
        atomicAdd(&spf[t * 36 + 16 + 4 * q + r], acc1[r]);
    }

    __syncthreads();   // main barrier

    // ---- masked band softmax + in-lane p handoff (R10/R11-verified layout) ----
    FragU pf;
    {
        const f32x4 s0 = *(const f32x4*)&spf[t * 36 + 4 * q];
        const f32x4 s1 = *(const f32x4*)&spf[t * 36 + 16 + 4 * q];
        float mx = -3.0e38f;
        #pragma unroll
        for (int r = 0; r < 4; ++r) {
            if ((unsigned)(4 * q + r - t) < 16u)      mx = fmaxf(mx, s0[r]);
            if ((unsigned)(4 * q + r + 16 - t) < 16u) mx = fmaxf(mx, s1[r]);
        }
        mx = fmaxf(mx, __shfl_xor(mx, 16));
        mx = fmaxf(mx, __shfl_xor(mx, 32));
        float p0[4], p1[4];
        float sum = 0.f;
        #pragma unroll
        for (int r = 0; r < 4; ++r) {
            const bool m0 = (unsigned)(4 * q + r - t) < 16u;
            const bool m1 = (unsigned)(4 * q + r + 16 - t) < 16u;
            p0[r] = m0 ? __expf(s0[r] - mx) : 0.f;
            p1[r] = m1 ? __expf(s1[r] - mx) : 0.f;
            sum += p0[r] + p1[r];
        }
        sum += __shfl_xor(sum, 16);
        sum += __shfl_xor(sum, 32);
        const float inv = 1.f / sum;
        #pragma unroll
        for (int r = 0; r < 4; ++r) { p0[r] *= inv; p1[r] *= inv; }

        if (w == 0) {
            #pragma unroll
            for (int r = 0; r < 4; ++r) {
                const int j0 = 4 * q + r;
                if ((unsigned)(j0 - t) < 16u)
                    p_out[(rowbase + t) * 16 + (j0 - t)] = p0[r];
                else
                    p_out[(rowbase + t) * 16 + (j0 + 16 - t)] = p1[r];
            }
        }
        pf.u[0] = pack_bf2(p0[0], p0[1]); pf.u[1] = pack_bf2(p0[2], p0[3]);
        pf.u[2] = pack_bf2(p1[0], p1[1]); pf.u[3] = pack_bf2(p1[2], p1[3]);
    }

    // ---- phase B: O^T tile = C^T · P^T from staged C (R11-verified) ----
    {
        #pragma unroll
        for (int m = 0; m < 4; ++m) {
            const int dc = w * 4 + m;           // d-chunk 0..31
            const int dA = dc * 16 + t;
            unsigned short cbits[8];
            #pragma unroll
            for (int e = 0; e < 8; ++e) {
                const int j = 4 * q + (e & 3) + 16 * (e >> 2);
                cbits[e] = cbuf[j * C_LDW + dA];
            }
            FragU af;
            af.u[0] = cbits[0] | ((unsigned)cbits[1] << 16);
            af.u[1] = cbits[2] | ((unsigned)cbits[3] << 16);
            af.u[2] = cbits[4] | ((unsigned)cbits[5] << 16);
            af.u[3] = cbits[6] | ((unsigned)cbits[7] << 16);
            f32x4 o = {0.f, 0.f, 0.f, 0.f};
            o = __builtin_amdgcn_mfma_f32_16x16x32_bf16(af.v, pf.v, o, 0, 0, 0);
            float* ob = out + (rowbase + t) * 1024 + dc * 16 + 4 * q;
            *(float4*)ob = make_float4(o[0], o[1], o[2], o[3]);
        }
    }
}

extern "C" void kernel_launch(void* const* d_in, const int* in_sizes, int n_in,
                              void* d_out, int out_size, void* d_ws, size_t ws_size,
                              hipStream_t stream) {
    const int*   symbols   = (const int*)d_in[0];
    const float* encodings = (const float*)d_in[1];
    const float* M         = (const float*)d_in[2];
    const float* C         = (const float*)d_in[3];
    float* out   = (float*)d_out;
    float* p_out = out + (size_t)B_ * T_ * 1024;   // concat order: output, then p

    dim3 grid(B_ * (T_ / 16));                     // 1024 blocks x 512 threads
    attn_cell_kernel<<<grid, 512, 0, stream>>>(symbols, encodings, M, C, out, p_out);
}